// Round 16
// baseline (123.178 us; speedup 1.0000x reference)
//
#include <hip/hip_runtime.h>

// Problem constants
constexpr int kT = 512;     // sequence length
constexpr int kF = 64;      // input features
constexpr int kC = 256;     // f_out
constexpr int kH = 4;       // heads
constexpr int kHD = 64;     // head dim
constexpr int kBN = 128;    // B*N independent problems

typedef __attribute__((ext_vector_type(4))) float f32x4;
typedef __attribute__((ext_vector_type(8))) short s16x8;
typedef __attribute__((ext_vector_type(4))) unsigned int u32x4;

__device__ inline unsigned short f2bf(float f) {
  unsigned int u = __float_as_uint(f);
  u += 0x7fff + ((u >> 16) & 1);  // round-to-nearest-even
  return (unsigned short)(u >> 16);
}

__device__ inline unsigned int cvt_pk(float a, float b) {  // lo=a, hi=b (RTNE)
  unsigned int w;
  asm("v_cvt_pk_bf16_f32 %0, %1, %2" : "=v"(w) : "v"(a), "v"(b));
  return w;
}

__device__ inline float max3f(float a, float b, float c) {
  return fmaxf(fmaxf(a, b), c);   // fuses to v_max3_f32
}

__device__ inline float exp2_hw(float x) {
  float r;
  asm("v_exp_f32 %0, %1" : "=v"(r) : "v"(x));
  return r;
}

// x^T B-frag straight from global: 8 f-strided dwords -> bf16x8 (RTNE)
__device__ inline s16x8 xgfrag(const float* __restrict__ xb0, int trow,
                               int fbase) {
  unsigned int wv[4];
#pragma unroll
  for (int jp = 0; jp < 4; ++jp) {
    float fa = xb0[(size_t)(fbase + 2 * jp) * kT + trow];
    float fb = xb0[(size_t)(fbase + 2 * jp + 1) * kT + trow];
    wv[jp] = cvt_pk(fa, fb);
  }
  return __builtin_bit_cast(s16x8, (u32x4){wv[0], wv[1], wv[2], wv[3]});
}

// ---------------------------------------------------------------------------
// Kernel 0: weight precompute.
// WB  [768][64]  = [Wq;Wk;Wv]^T rows c, cols f   (bf16)
// WoT [256][256] = Wo^T rows co, cols c          (bf16)
// ---------------------------------------------------------------------------
__global__ __launch_bounds__(256) void k_prep(
    const float* __restrict__ Wq, const float* __restrict__ Wk,
    const float* __restrict__ Wv, const float* __restrict__ Wo,
    unsigned short* __restrict__ WB, unsigned short* __restrict__ WoT) {
  int i = blockIdx.x * 256 + threadIdx.x;
  const int total = 768 * 64 + 256 * 256;
  for (; i < total; i += gridDim.x * 256) {
    if (i < 768 * 64) {
      int c = i >> 6, f = i & 63;
      int arr = c >> 8, cc = c & 255;
      const float* W = (arr == 0) ? Wq : (arr == 1) ? Wk : Wv;
      WB[i] = f2bf(W[f * 256 + cc]);
    } else {
      int j = i - 768 * 64;
      int co = j >> 8, c = j & 255;
      WoT[j] = f2bf(Wo[c * 256 + co]);
    }
  }
}

// ---------------------------------------------------------------------------
// Kernel 1: FUSED QKV + flash attention per (bn, head). 1024 thr = 16 waves.
// r16: BARRIER-FREE build. No xC staging: every wave reads its x B-frags
// directly from global (L1/L2-resident; same cvt_pk RTNE values -> identical
// math). Q up-front from global (r13-verified) + double-shfl redistribute;
// then each wave builds its 16 K/V tiles (4 chunks x 4 tiles) back-to-back
// into swizzled Kl / kappa-VtB. ONE __syncthreads total, then the r5-proven
// attention loop (defer-max exp2 softmax, in-register P, b128 K/V reads)
// with T5 s_setprio around MFMA clusters. LDS 128 KB -> 1 block/CU.
// ---------------------------------------------------------------------------
__global__ __launch_bounds__(1024, 4) void k_fattn(
    const float* __restrict__ x, const unsigned short* __restrict__ WB,
    const float* __restrict__ bq, const float* __restrict__ bk,
    const float* __restrict__ bv, unsigned short* __restrict__ Aw) {
  __shared__ __align__(16) unsigned char smem[131072];
  unsigned char* Kl = smem;                              // 64 KB [512][128B] swz
  unsigned char* VtB = smem + 65536;                     // 64 KB [64][1024B] swz

  const int tid = threadIdx.x;
  const int lbn = blockIdx.x >> 2;
  const int h = blockIdx.x & 3;
  const int lane = tid & 63, wid = tid >> 6;
  const int lr = lane & 15, lg = lane >> 4;
  const int swz = (lr & 7) << 4;

  const float kQscale = 0.180336880111120426f;  // 0.125 * log2(e)
  const unsigned short* WBq = WB + (size_t)(h * 64) * 64;
  const unsigned short* WBk = WB + (size_t)(256 + h * 64) * 64;
  const unsigned short* WBv = WB + (size_t)(512 + h * 64) * 64;
  const float* xb0 = x + (size_t)lbn * kF * kT;

  const int qbase = wid * 32;

  // ============ Q up-front, straight from global x (r13-verified) ============
  s16x8 qf[2][2];
  {
    f32x4 qa[2][4];
#pragma unroll
    for (int qt = 0; qt < 2; ++qt) {
      const int tq = qbase + qt * 16 + lr;
      s16x8 bfr0 = xgfrag(xb0, tq, lg * 8);
      s16x8 bfr1 = xgfrag(xb0, tq, 32 + lg * 8);
#pragma unroll
      for (int ct = 0; ct < 4; ++ct) {
        s16x8 af0 = *(const s16x8*)(WBq + (ct * 16 + lr) * 64 + lg * 8);
        s16x8 af1 = *(const s16x8*)(WBq + (ct * 16 + lr) * 64 + 32 + lg * 8);
        f32x4 a = {0.f, 0.f, 0.f, 0.f};
        a = __builtin_amdgcn_mfma_f32_16x16x32_bf16(af0, bfr0, a, 0, 0, 0);
        a = __builtin_amdgcn_mfma_f32_16x16x32_bf16(af1, bfr1, a, 0, 0, 0);
        const int dbase = ct * 16 + lg * 4;
#pragma unroll
        for (int r = 0; r < 4; ++r)
          a[r] = (a[r] + bq[h * 64 + dbase + r]) * kQscale;
        qa[qt][ct] = a;
      }
    }
    // redistribute: shuffle BOTH ct candidates, select AFTER with dest's sel
    const int sel = lg >> 1;
#pragma unroll
    for (int qt = 0; qt < 2; ++qt)
#pragma unroll
      for (int half = 0; half < 2; ++half) {
        unsigned int w[4];
#pragma unroll
        for (int i2 = 0; i2 < 4; ++i2) {
          const int r0 = (i2 & 1) * 2;
          const int lgp = (lg & 1) * 2 + (i2 >> 1);
          const int src = lgp * 16 + lr;
          float loA = __shfl(qa[qt][half * 2 + 0][r0], src);
          float hiA = __shfl(qa[qt][half * 2 + 1][r0], src);
          float loB = __shfl(qa[qt][half * 2 + 0][r0 + 1], src);
          float hiB = __shfl(qa[qt][half * 2 + 1][r0 + 1], src);
          w[i2] = cvt_pk(sel ? hiA : loA, sel ? hiB : loB);
        }
        qf[qt][half] =
            __builtin_bit_cast(s16x8, (u32x4){w[0], w[1], w[2], w[3]});
      }
  }

  // ============ barrier-free K/V build: 16 tiles per wave ============
  for (int tch = 0; tch < 4; ++tch) {
#pragma unroll
    for (int j = 0; j < 4; ++j) {
      const int tau = wid * 4 + j;
      const int isV = tau >> 5;
      const int tl = tau & 31;
      const int ct = tl >> 3, tt = tl & 7;
      const unsigned short* Wsrc = isV ? WBv : WBk;
      s16x8 af0 = *(const s16x8*)(Wsrc + (ct * 16 + lr) * 64 + lg * 8);
      s16x8 af1 = *(const s16x8*)(Wsrc + (ct * 16 + lr) * 64 + 32 + lg * 8);
      const int trow = tch * 128 + tt * 16 + lr;
      s16x8 bf0 = xgfrag(xb0, trow, lg * 8);
      s16x8 bf1 = xgfrag(xb0, trow, 32 + lg * 8);
      if (!isV) {
        // K: row = c(d), col = t -> lane holds 4 consecutive d at one t
        f32x4 a = {0.f, 0.f, 0.f, 0.f};
        a = __builtin_amdgcn_mfma_f32_16x16x32_bf16(af0, bf0, a, 0, 0, 0);
        a = __builtin_amdgcn_mfma_f32_16x16x32_bf16(af1, bf1, a, 0, 0, 0);
        const int dbase = ct * 16 + lg * 4;
        const int t = trow;
        uint2 pk;
        pk.x = cvt_pk(a[0] + bk[h * 64 + dbase + 0],
                      a[1] + bk[h * 64 + dbase + 1]);
        pk.y = cvt_pk(a[2] + bk[h * 64 + dbase + 2],
                      a[3] + bk[h * 64 + dbase + 3]);
        *(uint2*)(Kl + ((t * 128 + dbase * 2) ^ ((t & 7) << 4))) = pk;
      } else {
        // V swapped: row = t, col = d -> lane holds 4 consecutive t at one d
        f32x4 a = {0.f, 0.f, 0.f, 0.f};
        a = __builtin_amdgcn_mfma_f32_16x16x32_bf16(bf0, af0, a, 0, 0, 0);
        a = __builtin_amdgcn_mfma_f32_16x16x32_bf16(bf1, af1, a, 0, 0, 0);
        const int d = ct * 16 + lr;
        const float bias = bv[h * 64 + d];
        const int t0 = tch * 128 + tt * 16 + lg * 4;   // t0..t0+3, t0%4==0
        // kappa: pos = b32<<5 | hh<<3 | e<<2 | j2 for t = {b32,e,hh,j2}
        const int pos0 = ((t0 >> 5) << 5) | (((t0 >> 2) & 3) << 3) |
                         (((t0 >> 4) & 1) << 2);
        uint2 pk;
        pk.x = cvt_pk(a[0] + bias, a[1] + bias);
        pk.y = cvt_pk(a[2] + bias, a[3] + bias);
        *(uint2*)(VtB + ((d * 1024 + pos0 * 2) ^ ((d & 7) << 4))) = pk;
      }
    }
  }
  __syncthreads();  // the ONLY barrier: Kl/VtB complete

  // ============ attention (r5-proven) ============
  unsigned short* Ab = Aw + (size_t)lbn * kT * kC + h * kHD;

  f32x4 o0[4] = {{0,0,0,0},{0,0,0,0},{0,0,0,0},{0,0,0,0}};
  f32x4 o1[4] = {{0,0,0,0},{0,0,0,0},{0,0,0,0},{0,0,0,0}};
  float m0 = -3e38f, m1 = -3e38f, l0 = 0.f, l1 = 0.f;

  const int koff = (lg * 16) ^ swz;
  const unsigned char* kp0 = Kl + lr * 128 + koff;
  const unsigned char* kp1 = Kl + lr * 128 + (koff ^ 64);
  const unsigned char* vp0 = VtB + lr * 1024 + ((lg * 16) ^ swz);
  const unsigned char* vp1 = VtB + lr * 1024 + (((lg * 16) ^ 64) ^ swz);

  unsigned int w0[8], w1[8];

#define SOFTMAX_QT(sa, m, l, o, w)                                            \
  {                                                                           \
    float g0 = max3f(sa[0][0], sa[0][1], sa[0][2]);                           \
    float g1 = max3f(sa[0][3], sa[1][0], sa[1][1]);                           \
    float g2 = max3f(sa[1][2], sa[1][3], sa[2][0]);                           \
    float g3 = max3f(sa[2][1], sa[2][2], sa[2][3]);                           \
    float g4 = max3f(sa[3][0], sa[3][1], sa[3][2]);                           \
    float tm = fmaxf(max3f(g0, g1, g2), max3f(g3, g4, sa[3][3]));             \
    if (__any(tm > m + 8.0f)) {                                               \
      tm = fmaxf(tm, __shfl_xor(tm, 16));                                     \
      tm = fmaxf(tm, __shfl_xor(tm, 32));                                     \
      float mn = fmaxf(m, tm);                                                \
      float al = exp2_hw(m - mn);                                             \
      m = mn;                                                                 \
      l *= al;                                                                \
      float aq0 = __shfl(al, (lane & 48) | (lg * 4 + 0));                     \
      float aq1 = __shfl(al, (lane & 48) | (lg * 4 + 1));                     \
      float aq2 = __shfl(al, (lane & 48) | (lg * 4 + 2));                     \
      float aq3 = __shfl(al, (lane & 48) | (lg * 4 + 3));                     \
      _Pragma("unroll")                                                       \
      for (int dt = 0; dt < 4; ++dt) {                                        \
        o[dt][0] *= aq0; o[dt][1] *= aq1;                                     \
        o[dt][2] *= aq2; o[dt][3] *= aq3;                                     \
      }                                                                       \
    }                                                                         \
    _Pragma("unroll")                                                         \
    for (int s = 0; s < 4; ++s) {                                             \
      float e0 = exp2_hw(sa[s][0] - m);                                       \
      float e1 = exp2_hw(sa[s][1] - m);                                       \
      float e2 = exp2_hw(sa[s][2] - m);                                       \
      float e3 = exp2_hw(sa[s][3] - m);                                       \
      l += (e0 + e1) + (e2 + e3);                                             \
      w[2*s]   = cvt_pk(e0, e1);                                              \
      w[2*s+1] = cvt_pk(e2, e3);                                              \
    }                                                                         \
  }

  for (int kc = 0; kc < 8; ++kc) {
    f32x4 sa0[4], sa1[4];
    __builtin_amdgcn_s_setprio(1);
#pragma unroll
    for (int s = 0; s < 4; ++s) {
      s16x8 kf0 = *(const s16x8*)(kp0 + s * 2048);
      s16x8 kf1 = *(const s16x8*)(kp1 + s * 2048);
      f32x4 z0 = {0.f, 0.f, 0.f, 0.f};
      z0 = __builtin_amdgcn_mfma_f32_16x16x32_bf16(kf0, qf[0][0], z0, 0, 0, 0);
      z0 = __builtin_amdgcn_mfma_f32_16x16x32_bf16(kf1, qf[0][1], z0, 0, 0, 0);
      sa0[s] = z0;
      f32x4 z1 = {0.f, 0.f, 0.f, 0.f};
      z1 = __builtin_amdgcn_mfma_f32_16x16x32_bf16(kf0, qf[1][0], z1, 0, 0, 0);
      z1 = __builtin_amdgcn_mfma_f32_16x16x32_bf16(kf1, qf[1][1], z1, 0, 0, 0);
      sa1[s] = z1;
    }
    __builtin_amdgcn_s_setprio(0);
    kp0 += 8192;
    kp1 += 8192;

    // V reads issued before softmax: latency hides under the VALU chain
    s16x8 vb0[4], vb1[4];
#pragma unroll
    for (int dt = 0; dt < 4; ++dt) {
      vb0[dt] = *(const s16x8*)(vp0 + dt * 16384);
      vb1[dt] = *(const s16x8*)(vp1 + dt * 16384);
    }
    vp0 += 128;
    vp1 += 128;

    SOFTMAX_QT(sa0, m0, l0, o0, w0)
    SOFTMAX_QT(sa1, m1, l1, o1, w1)

    s16x8 pa00 = __builtin_bit_cast(s16x8, (u32x4){w0[0], w0[1], w0[2], w0[3]});
    s16x8 pa01 = __builtin_bit_cast(s16x8, (u32x4){w0[4], w0[5], w0[6], w0[7]});
    s16x8 pa10 = __builtin_bit_cast(s16x8, (u32x4){w1[0], w1[1], w1[2], w1[3]});
    s16x8 pa11 = __builtin_bit_cast(s16x8, (u32x4){w1[4], w1[5], w1[6], w1[7]});

    __builtin_amdgcn_s_setprio(1);
#pragma unroll
    for (int dt = 0; dt < 4; ++dt) {
      o0[dt] = __builtin_amdgcn_mfma_f32_16x16x32_bf16(pa00, vb0[dt], o0[dt], 0, 0, 0);
      o1[dt] = __builtin_amdgcn_mfma_f32_16x16x32_bf16(pa10, vb0[dt], o1[dt], 0, 0, 0);
    }
#pragma unroll
    for (int dt = 0; dt < 4; ++dt) {
      o0[dt] = __builtin_amdgcn_mfma_f32_16x16x32_bf16(pa01, vb1[dt], o0[dt], 0, 0, 0);
      o1[dt] = __builtin_amdgcn_mfma_f32_16x16x32_bf16(pa11, vb1[dt], o1[dt], 0, 0, 0);
    }
    __builtin_amdgcn_s_setprio(0);
  }
#undef SOFTMAX_QT

  // epilogue: cross-lane l sum, normalize, write (cvt_pk packing)
#pragma unroll
  for (int qt = 0; qt < 2; ++qt) {
    float l = (qt == 0) ? l0 : l1;
    f32x4* o = (qt == 0) ? o0 : o1;
    float l2 = l + __shfl_xor(l, 16);
    float lr4 = l2 + __shfl_xor(l2, 32);
    float li0 = 1.0f / __shfl(lr4, (lane & 48) | (lg * 4 + 0));
    float li1 = 1.0f / __shfl(lr4, (lane & 48) | (lg * 4 + 1));
    float li2 = 1.0f / __shfl(lr4, (lane & 48) | (lg * 4 + 2));
    float li3 = 1.0f / __shfl(lr4, (lane & 48) | (lg * 4 + 3));
    const int qb = qbase + qt * 16;
#pragma unroll
    for (int r = 0; r < 4; ++r) {
      float li = (r == 0) ? li0 : (r == 1) ? li1 : (r == 2) ? li2 : li3;
      unsigned short* orow = Ab + (size_t)(qb + lg * 4 + r) * kC;
      unsigned int wa = cvt_pk(o[0][r] * li, o[1][r] * li);
      unsigned int wb = cvt_pk(o[2][r] * li, o[3][r] * li);
      orow[0 * 16 + lr] = (unsigned short)wa;
      orow[1 * 16 + lr] = (unsigned short)(wa >> 16);
      orow[2 * 16 + lr] = (unsigned short)wb;
      orow[3 * 16 + lr] = (unsigned short)(wb >> 16);
    }
  }
}

// ---------------------------------------------------------------------------
// Kernel 3: output projection + bias + transpose. Block = (bn, 128-t chunk),
// 512 thr = 8 waves (2 t-halves x 4 co-quads). A staged ONCE in swizzled LDS.
// out[bn][co][t] fp32.
// ---------------------------------------------------------------------------
__global__ __launch_bounds__(512) void k_proj(
    const unsigned short* __restrict__ Aw, const unsigned short* __restrict__ WoT,
    const float* __restrict__ bo, float* __restrict__ out) {
  __shared__ __align__(16) unsigned char Al[128 * 512];  // [t][c] swizzled, 64KB

  const int tid = threadIdx.x;
  const int lbn = blockIdx.x >> 2;
  const int tch = blockIdx.x & 3;
  const int t0 = tch * 128;

  const uint4* Asrc = (const uint4*)(Aw + ((size_t)lbn * kT + t0) * kC);
#pragma unroll
  for (int i = 0; i < 8; ++i) {
    int idx = tid + i * 512;
    int trow = idx >> 5, cc = idx & 31;
    *(uint4*)(Al + ((trow * 512 + cc * 16) ^ ((trow & 7) << 4))) = Asrc[idx];
  }
  __syncthreads();

  const int lane = tid & 63, wid = tid >> 6;
  const int lr = lane & 15, lg = lane >> 4;
  const int swz = (lr & 7) << 4;
  const int tb = (wid >> 2) * 64;
  const int cob = (wid & 3) * 64;

  float* ob = out + (size_t)lbn * kC * kT;

  for (int ci = 0; ci < 4; ++ci) {
    const int co0 = cob + ci * 16;
    s16x8 af[8];
#pragma unroll
    for (int kc = 0; kc < 8; ++kc)
      af[kc] = *(const s16x8*)(WoT + (size_t)(co0 + lr) * 256 + kc * 32 + lg * 8);
    float b4[4];
#pragma unroll
    for (int r = 0; r < 4; ++r) b4[r] = bo[co0 + lg * 4 + r];

#pragma unroll
    for (int tj = 0; tj < 4; ++tj) {
      const unsigned char* ap = Al + (tb + tj * 16 + lr) * 512;
      f32x4 acc = {0.f, 0.f, 0.f, 0.f};
#pragma unroll
      for (int kc = 0; kc < 8; ++kc) {
        s16x8 bfr = *(const s16x8*)(ap + ((kc * 64 + lg * 16) ^ swz));
        acc = __builtin_amdgcn_mfma_f32_16x16x32_bf16(af[kc], bfr, acc, 0, 0, 0);
      }
      int t = t0 + tb + tj * 16 + lr;
#pragma unroll
      for (int r = 0; r < 4; ++r)
        ob[(size_t)(co0 + lg * 4 + r) * kT + t] = acc[r] + b4[r];
    }
  }
}

// ---------------------------------------------------------------------------
extern "C" void kernel_launch(void* const* d_in, const int* in_sizes, int n_in,
                              void* d_out, int out_size, void* d_ws, size_t ws_size,
                              hipStream_t stream) {
  const float* x  = (const float*)d_in[0];
  const float* Wq = (const float*)d_in[1];
  const float* bq = (const float*)d_in[2];
  const float* Wk = (const float*)d_in[3];
  const float* bk = (const float*)d_in[4];
  const float* Wv = (const float*)d_in[5];
  const float* bv = (const float*)d_in[6];
  const float* Wo = (const float*)d_in[7];
  const float* bo = (const float*)d_in[8];
  float* out = (float*)d_out;

  // ws layout: WB bf16 [768*64] | WoT bf16 [256*256] | A bf16 [128*512*256]
  const size_t wElems = 768 * 64 + 256 * 256;             // 229376 B
  const size_t aBytes = (size_t)kBN * kT * kC * 2;        // 32 MB
  if (ws_size < wElems * 2 + aBytes) return;

  unsigned short* WB  = (unsigned short*)d_ws;
  unsigned short* WoT = WB + 768 * 64;
  unsigned short* A   = WB + wElems;

  k_prep<<<dim3(448), dim3(256), 0, stream>>>(Wq, Wk, Wv, Wo, WB, WoT);
  k_fattn<<<dim3(kBN * kH), dim3(1024), 0, stream>>>(x, WB, bq, bk, bv, A);
  k_proj<<<dim3(kBN * 4), dim3(512), 0, stream>>>(A, WoT, bo, out);
}

// Round 18
// 118.167 us; speedup vs baseline: 1.0424x; 1.0424x over previous
//
#include <hip/hip_runtime.h>

// Problem constants
constexpr int kT = 512;     // sequence length
constexpr int kF = 64;      // input features
constexpr int kC = 256;     // f_out
constexpr int kH = 4;       // heads
constexpr int kHD = 64;     // head dim
constexpr int kBN = 128;    // B*N independent problems

typedef __attribute__((ext_vector_type(4))) float f32x4;
typedef __attribute__((ext_vector_type(8))) short s16x8;
typedef __attribute__((ext_vector_type(4))) unsigned int u32x4;

__device__ inline unsigned short f2bf(float f) {
  unsigned int u = __float_as_uint(f);
  u += 0x7fff + ((u >> 16) & 1);  // round-to-nearest-even
  return (unsigned short)(u >> 16);
}

__device__ inline float max3f(float a, float b, float c) {
  return fmaxf(fmaxf(a, b), c);   // fuses to v_max3_f32
}

__device__ inline float exp2_hw(float x) {
  float r;
  asm("v_exp_f32 %0, %1" : "=v"(r) : "v"(x));
  return r;
}

// ---------------------------------------------------------------------------
// Kernel 0: weight precompute.
// WB  [768][64]  = [Wq;Wk;Wv]^T rows c, cols f   (bf16)
// WoT [256][256] = Wo^T rows co, cols c          (bf16)
// ---------------------------------------------------------------------------
__global__ __launch_bounds__(256) void k_prep(
    const float* __restrict__ Wq, const float* __restrict__ Wk,
    const float* __restrict__ Wv, const float* __restrict__ Wo,
    unsigned short* __restrict__ WB, unsigned short* __restrict__ WoT) {
  int i = blockIdx.x * 256 + threadIdx.x;
  const int total = 768 * 64 + 256 * 256;
  for (; i < total; i += gridDim.x * 256) {
    if (i < 768 * 64) {
      int c = i >> 6, f = i & 63;
      int arr = c >> 8, cc = c & 255;
      const float* W = (arr == 0) ? Wq : (arr == 1) ? Wk : Wv;
      WB[i] = f2bf(W[f * 256 + cc]);
    } else {
      int j = i - 768 * 64;
      int co = j >> 8, c = j & 255;
      WoT[j] = f2bf(Wo[c * 256 + co]);
    }
  }
}

// ---------------------------------------------------------------------------
// Kernel 1: FUSED QKV + flash attention per (bn, head). 1024 thr = 16 waves.
// Per 128-t chunk: stage x^T (bf16) -> all waves compute K (packed 8B
// [t][d] swizzled store) and V (operand-swapped mfma -> row=t layout ->
// single packed 8B kappa-store into [d][pos]); the 4 q-owning waves also
// compute Q and redistribute into B-frag layout via in-register shfl
// (shuffle BOTH d-half registers, select AFTER with the dest lane's sel).
// 2 barriers per chunk. Attention loop: r5-proven (defer-max exp2 softmax,
// in-register P, b128 K/V reads). LDS 146 KB -> 1 block/CU. Spill-free at
// VGPR 60 (verified r11/r15: WRITE_SIZE == A exactly).
// ---------------------------------------------------------------------------
__global__ __launch_bounds__(1024, 4) void k_fattn(
    const float* __restrict__ x, const unsigned short* __restrict__ WB,
    const float* __restrict__ bq, const float* __restrict__ bk,
    const float* __restrict__ bv, unsigned short* __restrict__ Aw) {
  __shared__ __align__(16) unsigned char smem[149504];
  unsigned char* Kl = smem;                              // 64 KB  [512][128B] swz
  unsigned char* VtB = smem + 65536;                     // 64 KB  [64][1024B] swz
  unsigned short* xC = (unsigned short*)(smem + 131072); // 18 KB  [128][72] u16

  const int tid = threadIdx.x;
  const int lbn = blockIdx.x >> 2;
  const int h = blockIdx.x & 3;
  const int lane = tid & 63, wid = tid >> 6;
  const int lr = lane & 15, lg = lane >> 4;
  const int swz = (lr & 7) << 4;

  const float kQscale = 0.180336880111120426f;  // 0.125 * log2(e)
  const unsigned short* WBq = WB + (size_t)(h * 64) * 64;
  const unsigned short* WBk = WB + (size_t)(256 + h * 64) * 64;
  const unsigned short* WBv = WB + (size_t)(512 + h * 64) * 64;

  s16x8 qf[2][2];

  // ============ QKV build (2 barriers per chunk) ============
  for (int tch = 0; tch < 4; ++tch) {
    __syncthreads();  // prior-phase xC reads done before overwrite
    const float* xb = x + (size_t)lbn * kF * kT + tch * 128;
#pragma unroll
    for (int it = 0; it < 2; ++it) {
      int idx = tid + it * 1024;
      int f = idx >> 5, t4 = idx & 31;
      float4 v = *(const float4*)(xb + f * kT + t4 * 4);
      xC[(t4 * 4 + 0) * 72 + f] = f2bf(v.x);
      xC[(t4 * 4 + 1) * 72 + f] = f2bf(v.y);
      xC[(t4 * 4 + 2) * 72 + f] = f2bf(v.z);
      xC[(t4 * 4 + 3) * 72 + f] = f2bf(v.w);
    }
    __syncthreads();  // xC ready

    // K/V tiles: tau = wid*4 + j ; tau<32 -> K(ct=tau>>3,tt=tau&7), else V
#pragma unroll
    for (int j = 0; j < 4; ++j) {
      const int tau = wid * 4 + j;
      const int isV = tau >> 5;
      const int tl = tau & 31;
      const int ct = tl >> 3, tt = tl & 7;
      const unsigned short* Wsrc = isV ? WBv : WBk;
      s16x8 af0 = *(const s16x8*)(Wsrc + (ct * 16 + lr) * 64 + lg * 8);
      s16x8 af1 = *(const s16x8*)(Wsrc + (ct * 16 + lr) * 64 + 32 + lg * 8);
      s16x8 bf0 = *(const s16x8*)&xC[(tt * 16 + lr) * 72 + lg * 8];
      s16x8 bf1 = *(const s16x8*)&xC[(tt * 16 + lr) * 72 + 32 + lg * 8];
      if (!isV) {
        // K: row = c(d), col = t -> lane holds 4 consecutive d at one t
        f32x4 a = {0.f, 0.f, 0.f, 0.f};
        a = __builtin_amdgcn_mfma_f32_16x16x32_bf16(af0, bf0, a, 0, 0, 0);
        a = __builtin_amdgcn_mfma_f32_16x16x32_bf16(af1, bf1, a, 0, 0, 0);
        const int dbase = ct * 16 + lg * 4;
        const int t = tch * 128 + tt * 16 + lr;
        float v0 = a[0] + bk[h * 64 + dbase + 0];
        float v1 = a[1] + bk[h * 64 + dbase + 1];
        float v2 = a[2] + bk[h * 64 + dbase + 2];
        float v3 = a[3] + bk[h * 64 + dbase + 3];
        unsigned long long pk =
            (unsigned long long)f2bf(v0) |
            ((unsigned long long)f2bf(v1) << 16) |
            ((unsigned long long)f2bf(v2) << 32) |
            ((unsigned long long)f2bf(v3) << 48);
        *(unsigned long long*)(Kl + ((t * 128 + dbase * 2) ^ ((t & 7) << 4))) = pk;
      } else {
        // V swapped: row = t, col = d -> lane holds 4 consecutive t at one d
        f32x4 a = {0.f, 0.f, 0.f, 0.f};
        a = __builtin_amdgcn_mfma_f32_16x16x32_bf16(bf0, af0, a, 0, 0, 0);
        a = __builtin_amdgcn_mfma_f32_16x16x32_bf16(bf1, af1, a, 0, 0, 0);
        const int d = ct * 16 + lr;
        const float bias = bv[h * 64 + d];
        const int t0 = tch * 128 + tt * 16 + lg * 4;   // t0..t0+3, t0%4==0
        // kappa: pos = b32<<5 | hh<<3 | e<<2 | j2 for t = {b32,e,hh,j2}
        const int pos0 = ((t0 >> 5) << 5) | (((t0 >> 2) & 3) << 3) |
                         (((t0 >> 4) & 1) << 2);
        unsigned long long pk =
            (unsigned long long)f2bf(a[0] + bias) |
            ((unsigned long long)f2bf(a[1] + bias) << 16) |
            ((unsigned long long)f2bf(a[2] + bias) << 32) |
            ((unsigned long long)f2bf(a[3] + bias) << 48);
        *(unsigned long long*)(VtB + ((d * 1024 + pos0 * 2) ^ ((d & 7) << 4))) = pk;
      }
    }

    // Q: the 4 waves owning this chunk's q-rows; register-only redistribute
    if ((wid >> 2) == tch) {
      f32x4 qa[2][4];
#pragma unroll
      for (int qt = 0; qt < 2; ++qt) {
        const int ttq = (wid & 3) * 2 + qt;
#pragma unroll
        for (int ct = 0; ct < 4; ++ct) {
          s16x8 af0 = *(const s16x8*)(WBq + (ct * 16 + lr) * 64 + lg * 8);
          s16x8 af1 = *(const s16x8*)(WBq + (ct * 16 + lr) * 64 + 32 + lg * 8);
          s16x8 bf0 = *(const s16x8*)&xC[(ttq * 16 + lr) * 72 + lg * 8];
          s16x8 bf1 = *(const s16x8*)&xC[(ttq * 16 + lr) * 72 + 32 + lg * 8];
          f32x4 a = {0.f, 0.f, 0.f, 0.f};
          a = __builtin_amdgcn_mfma_f32_16x16x32_bf16(af0, bf0, a, 0, 0, 0);
          a = __builtin_amdgcn_mfma_f32_16x16x32_bf16(af1, bf1, a, 0, 0, 0);
          const int dbase = ct * 16 + lg * 4;
#pragma unroll
          for (int r = 0; r < 4; ++r)
            a[r] = (a[r] + bq[h * 64 + dbase + r]) * kQscale;
          qa[qt][ct] = a;
        }
      }
      // qf[qt][half][j] = qa[qt][half*2+(lg>>1)][j&3] from lane
      // ((lg&1)*2+(j>>2))*16+lr ; shuffle BOTH candidates, select after.
      const int sel = lg >> 1;
#pragma unroll
      for (int qt = 0; qt < 2; ++qt)
#pragma unroll
        for (int half = 0; half < 2; ++half) {
          unsigned int w[4];
#pragma unroll
          for (int i2 = 0; i2 < 4; ++i2) {
            const int r0 = (i2 & 1) * 2;
            const int lgp = (lg & 1) * 2 + (i2 >> 1);
            const int src = lgp * 16 + lr;
            float loA = __shfl(qa[qt][half * 2 + 0][r0], src);
            float hiA = __shfl(qa[qt][half * 2 + 1][r0], src);
            float loB = __shfl(qa[qt][half * 2 + 0][r0 + 1], src);
            float hiB = __shfl(qa[qt][half * 2 + 1][r0 + 1], src);
            float eA = sel ? hiA : loA;
            float eB = sel ? hiB : loB;
            asm("v_cvt_pk_bf16_f32 %0, %1, %2"
                : "=v"(w[i2]) : "v"(eA), "v"(eB));
          }
          qf[qt][half] =
              __builtin_bit_cast(s16x8, (u32x4){w[0], w[1], w[2], w[3]});
        }
    }
  }
  __syncthreads();  // Kl/VtB complete

  // ============ attention (r5-proven) ============
  unsigned short* Ab = Aw + (size_t)lbn * kT * kC + h * kHD;
  const int qbase = wid * 32;

  f32x4 o0[4] = {{0,0,0,0},{0,0,0,0},{0,0,0,0},{0,0,0,0}};
  f32x4 o1[4] = {{0,0,0,0},{0,0,0,0},{0,0,0,0},{0,0,0,0}};
  float m0 = -3e38f, m1 = -3e38f, l0 = 0.f, l1 = 0.f;

  const int koff = (lg * 16) ^ swz;
  const unsigned char* kp0 = Kl + lr * 128 + koff;
  const unsigned char* kp1 = Kl + lr * 128 + (koff ^ 64);
  const unsigned char* vp0 = VtB + lr * 1024 + ((lg * 16) ^ swz);
  const unsigned char* vp1 = VtB + lr * 1024 + (((lg * 16) ^ 64) ^ swz);

  unsigned int w0[8], w1[8];

#define SOFTMAX_QT(sa, m, l, o, w)                                            \
  {                                                                           \
    float g0 = max3f(sa[0][0], sa[0][1], sa[0][2]);                           \
    float g1 = max3f(sa[0][3], sa[1][0], sa[1][1]);                           \
    float g2 = max3f(sa[1][2], sa[1][3], sa[2][0]);                           \
    float g3 = max3f(sa[2][1], sa[2][2], sa[2][3]);                           \
    float g4 = max3f(sa[3][0], sa[3][1], sa[3][2]);                           \
    float tm = fmaxf(max3f(g0, g1, g2), max3f(g3, g4, sa[3][3]));             \
    if (__any(tm > m + 8.0f)) {                                               \
      tm = fmaxf(tm, __shfl_xor(tm, 16));                                     \
      tm = fmaxf(tm, __shfl_xor(tm, 32));                                     \
      float mn = fmaxf(m, tm);                                                \
      float al = exp2_hw(m - mn);                                             \
      m = mn;                                                                 \
      l *= al;                                                                \
      float aq0 = __shfl(al, (lane & 48) | (lg * 4 + 0));                     \
      float aq1 = __shfl(al, (lane & 48) | (lg * 4 + 1));                     \
      float aq2 = __shfl(al, (lane & 48) | (lg * 4 + 2));                     \
      float aq3 = __shfl(al, (lane & 48) | (lg * 4 + 3));                     \
      _Pragma("unroll")                                                       \
      for (int dt = 0; dt < 4; ++dt) {                                        \
        o[dt][0] *= aq0; o[dt][1] *= aq1;                                     \
        o[dt][2] *= aq2; o[dt][3] *= aq3;                                     \
      }                                                                       \
    }                                                                         \
    _Pragma("unroll")                                                         \
    for (int s = 0; s < 4; ++s) {                                             \
      float e0 = exp2_hw(sa[s][0] - m);                                       \
      float e1 = exp2_hw(sa[s][1] - m);                                       \
      float e2 = exp2_hw(sa[s][2] - m);                                       \
      float e3 = exp2_hw(sa[s][3] - m);                                       \
      l += (e0 + e1) + (e2 + e3);                                             \
      asm("v_cvt_pk_bf16_f32 %0, %1, %2" : "=v"(w[2*s]) : "v"(e0), "v"(e1));  \
      asm("v_cvt_pk_bf16_f32 %0, %1, %2" : "=v"(w[2*s+1]) : "v"(e2), "v"(e3));\
    }                                                                         \
  }

  for (int kc = 0; kc < 8; ++kc) {
    f32x4 sa0[4], sa1[4];
#pragma unroll
    for (int s = 0; s < 4; ++s) {
      s16x8 kf0 = *(const s16x8*)(kp0 + s * 2048);
      s16x8 kf1 = *(const s16x8*)(kp1 + s * 2048);
      f32x4 z0 = {0.f, 0.f, 0.f, 0.f};
      z0 = __builtin_amdgcn_mfma_f32_16x16x32_bf16(kf0, qf[0][0], z0, 0, 0, 0);
      z0 = __builtin_amdgcn_mfma_f32_16x16x32_bf16(kf1, qf[0][1], z0, 0, 0, 0);
      sa0[s] = z0;
      f32x4 z1 = {0.f, 0.f, 0.f, 0.f};
      z1 = __builtin_amdgcn_mfma_f32_16x16x32_bf16(kf0, qf[1][0], z1, 0, 0, 0);
      z1 = __builtin_amdgcn_mfma_f32_16x16x32_bf16(kf1, qf[1][1], z1, 0, 0, 0);
      sa1[s] = z1;
    }
    kp0 += 8192;
    kp1 += 8192;

    SOFTMAX_QT(sa0, m0, l0, o0, w0)
    SOFTMAX_QT(sa1, m1, l1, o1, w1)

    s16x8 pa00 = __builtin_bit_cast(s16x8, (u32x4){w0[0], w0[1], w0[2], w0[3]});
    s16x8 pa01 = __builtin_bit_cast(s16x8, (u32x4){w0[4], w0[5], w0[6], w0[7]});
    s16x8 pa10 = __builtin_bit_cast(s16x8, (u32x4){w1[0], w1[1], w1[2], w1[3]});
    s16x8 pa11 = __builtin_bit_cast(s16x8, (u32x4){w1[4], w1[5], w1[6], w1[7]});

#pragma unroll
    for (int dt = 0; dt < 4; ++dt) {
      s16x8 vb = *(const s16x8*)(vp0 + dt * 16384);
      o0[dt] = __builtin_amdgcn_mfma_f32_16x16x32_bf16(pa00, vb, o0[dt], 0, 0, 0);
      o1[dt] = __builtin_amdgcn_mfma_f32_16x16x32_bf16(pa10, vb, o1[dt], 0, 0, 0);
    }
#pragma unroll
    for (int dt = 0; dt < 4; ++dt) {
      s16x8 vb = *(const s16x8*)(vp1 + dt * 16384);
      o0[dt] = __builtin_amdgcn_mfma_f32_16x16x32_bf16(pa01, vb, o0[dt], 0, 0, 0);
      o1[dt] = __builtin_amdgcn_mfma_f32_16x16x32_bf16(pa11, vb, o1[dt], 0, 0, 0);
    }
    vp0 += 128;
    vp1 += 128;
  }
#undef SOFTMAX_QT

  // epilogue: cross-lane l sum, normalize, write
#pragma unroll
  for (int qt = 0; qt < 2; ++qt) {
    float l = (qt == 0) ? l0 : l1;
    f32x4* o = (qt == 0) ? o0 : o1;
    float l2 = l + __shfl_xor(l, 16);
    float lr4 = l2 + __shfl_xor(l2, 32);
    float li0 = 1.0f / __shfl(lr4, (lane & 48) | (lg * 4 + 0));
    float li1 = 1.0f / __shfl(lr4, (lane & 48) | (lg * 4 + 1));
    float li2 = 1.0f / __shfl(lr4, (lane & 48) | (lg * 4 + 2));
    float li3 = 1.0f / __shfl(lr4, (lane & 48) | (lg * 4 + 3));
    const int qb = qbase + qt * 16;
#pragma unroll
    for (int r = 0; r < 4; ++r) {
      float li = (r == 0) ? li0 : (r == 1) ? li1 : (r == 2) ? li2 : li3;
      unsigned short* orow = Ab + (size_t)(qb + lg * 4 + r) * kC;
#pragma unroll
      for (int dt = 0; dt < 4; ++dt)
        orow[dt * 16 + lr] = f2bf(o[dt][r] * li);
    }
  }
}

// ---------------------------------------------------------------------------
// Kernel 3: output projection + bias + transpose. Block = (bn, 128-t chunk),
// 512 thr = 8 waves (2 t-halves x 4 co-quads). A staged ONCE in swizzled LDS.
// out[bn][co][t] fp32.
// ---------------------------------------------------------------------------
__global__ __launch_bounds__(512) void k_proj(
    const unsigned short* __restrict__ Aw, const unsigned short* __restrict__ WoT,
    const float* __restrict__ bo, float* __restrict__ out) {
  __shared__ __align__(16) unsigned char Al[128 * 512];  // [t][c] swizzled, 64KB

  const int tid = threadIdx.x;
  const int lbn = blockIdx.x >> 2;
  const int tch = blockIdx.x & 3;
  const int t0 = tch * 128;

  const uint4* Asrc = (const uint4*)(Aw + ((size_t)lbn * kT + t0) * kC);
#pragma unroll
  for (int i = 0; i < 8; ++i) {
    int idx = tid + i * 512;
    int trow = idx >> 5, cc = idx & 31;
    *(uint4*)(Al + ((trow * 512 + cc * 16) ^ ((trow & 7) << 4))) = Asrc[idx];
  }
  __syncthreads();

  const int lane = tid & 63, wid = tid >> 6;
  const int lr = lane & 15, lg = lane >> 4;
  const int swz = (lr & 7) << 4;
  const int tb = (wid >> 2) * 64;
  const int cob = (wid & 3) * 64;

  float* ob = out + (size_t)lbn * kC * kT;

  for (int ci = 0; ci < 4; ++ci) {
    const int co0 = cob + ci * 16;
    s16x8 af[8];
#pragma unroll
    for (int kc = 0; kc < 8; ++kc)
      af[kc] = *(const s16x8*)(WoT + (size_t)(co0 + lr) * 256 + kc * 32 + lg * 8);
    float b4[4];
#pragma unroll
    for (int r = 0; r < 4; ++r) b4[r] = bo[co0 + lg * 4 + r];

#pragma unroll
    for (int tj = 0; tj < 4; ++tj) {
      const unsigned char* ap = Al + (tb + tj * 16 + lr) * 512;
      f32x4 acc = {0.f, 0.f, 0.f, 0.f};
#pragma unroll
      for (int kc = 0; kc < 8; ++kc) {
        s16x8 bfr = *(const s16x8*)(ap + ((kc * 64 + lg * 16) ^ swz));
        acc = __builtin_amdgcn_mfma_f32_16x16x32_bf16(af[kc], bfr, acc, 0, 0, 0);
      }
      int t = t0 + tb + tj * 16 + lr;
#pragma unroll
      for (int r = 0; r < 4; ++r)
        ob[(size_t)(co0 + lg * 4 + r) * kT + t] = acc[r] + b4[r];
    }
  }
}

// ---------------------------------------------------------------------------
extern "C" void kernel_launch(void* const* d_in, const int* in_sizes, int n_in,
                              void* d_out, int out_size, void* d_ws, size_t ws_size,
                              hipStream_t stream) {
  const float* x  = (const float*)d_in[0];
  const float* Wq = (const float*)d_in[1];
  const float* bq = (const float*)d_in[2];
  const float* Wk = (const float*)d_in[3];
  const float* bk = (const float*)d_in[4];
  const float* Wv = (const float*)d_in[5];
  const float* bv = (const float*)d_in[6];
  const float* Wo = (const float*)d_in[7];
  const float* bo = (const float*)d_in[8];
  float* out = (float*)d_out;

  // ws layout: WB bf16 [768*64] | WoT bf16 [256*256] | A bf16 [128*512*256]
  const size_t wElems = 768 * 64 + 256 * 256;             // 229376 B
  const size_t aBytes = (size_t)kBN * kT * kC * 2;        // 32 MB
  if (ws_size < wElems * 2 + aBytes) return;

  unsigned short* WB  = (unsigned short*)d_ws;
  unsigned short* WoT = WB + 768 * 64;
  unsigned short* A   = WB + wElems;

  k_prep<<<dim3(448), dim3(256), 0, stream>>>(Wq, Wk, Wv, Wo, WB, WoT);
  k_fattn<<<dim3(kBN * kH), dim3(1024), 0, stream>>>(x, WB, bq, bk, bv, A);
  k_proj<<<dim3(kBN * 4), dim3(512), 0, stream>>>(A, WoT, bo, out);
}